// Round 1
// baseline (703.786 us; speedup 1.0000x reference)
//
#include <hip/hip_runtime.h>
#include <math.h>

#define Bb 8
#define Tt 4
#define Nn 2048
#define Dd 256
#define Mm 4096
#define Ee 8
#define ROWS (Bb*Nn)   // 16384
#define KSEL 8

// output offsets (floats)
#define O_GATE 0LL
#define O_MEMR 131072LL
#define O_LABR 4325376LL
#define O_MLAB 4456448LL
#define O_ATTW 4489216LL

// ---------------- K0: transpose W (256x256) into ws ----------------
__global__ void k_transpose(const float* __restrict__ W, float* __restrict__ WT) {
    int i = blockIdx.x * 256 + threadIdx.x;   // 0..65535
    int r = i >> 8, c = i & 255;
    WT[c * 256 + r] = W[r * 256 + c];
}

// ---------------- K1: x = mean_T(prop); q = tanh(x @ W^T + b) ----------------
__global__ __launch_bounds__(256) void k_q(const float* __restrict__ prop,
                                           const float* __restrict__ WT,
                                           const float* __restrict__ bias,
                                           float* __restrict__ q) {
    __shared__ float xs[16][256];
    int tid = threadIdx.x;
    int row0 = blockIdx.x * 16;
    #pragma unroll
    for (int r = 0; r < 16; ++r) {
        int row = row0 + r;
        int b = row >> 11;       // / 2048
        int n = row & 2047;
        const float* p = prop + ((long long)(b * Tt) * Nn + n) * Dd + tid;
        float s = 0.f;
        #pragma unroll
        for (int t = 0; t < Tt; ++t) s += p[(long long)t * Nn * Dd];
        xs[r][tid] = s * 0.25f;
    }
    __syncthreads();
    float acc[16];
    #pragma unroll
    for (int r = 0; r < 16; ++r) acc[r] = 0.f;
    int c = tid;
    for (int d = 0; d < 256; ++d) {
        float wv = WT[d * 256 + c];
        #pragma unroll
        for (int r = 0; r < 16; ++r) acc[r] = fmaf(xs[r][d], wv, acc[r]);
    }
    float bv = bias[c];
    #pragma unroll
    for (int r = 0; r < 16; ++r)
        q[(long long)(row0 + r) * Dd + c] = tanhf(acc[r] + bv);
}

// ---------------- K2: mem_label = softmax(mem @ w_gate) ----------------
__global__ __launch_bounds__(256) void k_mlabel(const float* __restrict__ mem,
                                                const float* __restrict__ wg,
                                                float* __restrict__ mlab) {
    int m = blockIdx.x * 256 + threadIdx.x;
    if (m >= Mm) return;
    float acc[Ee];
    #pragma unroll
    for (int e = 0; e < Ee; ++e) acc[e] = 0.f;
    const float* mr = mem + (long long)m * Dd;
    for (int d = 0; d < Dd; ++d) {
        float mv = mr[d];
        #pragma unroll
        for (int e = 0; e < Ee; ++e) acc[e] = fmaf(mv, wg[d * Ee + e], acc[e]);
    }
    float mx = acc[0];
    #pragma unroll
    for (int e = 1; e < Ee; ++e) mx = fmaxf(mx, acc[e]);
    float z = 0.f;
    #pragma unroll
    for (int e = 0; e < Ee; ++e) { acc[e] = expf(acc[e] - mx); z += acc[e]; }
    float inv = 1.f / z;
    #pragma unroll
    for (int e = 0; e < Ee; ++e) mlab[(long long)m * Ee + e] = acc[e] * inv;
}

// ---------------- K3: att = q @ key^T (fp32 tiled GEMM, 128x128x16) ----------------
__global__ __launch_bounds__(256) void k_att(const float* __restrict__ q,
                                             const float* __restrict__ key,
                                             float* __restrict__ att) {
    __shared__ float As[16][128];
    __shared__ float Bs[16][128];
    int tid = threadIdx.x;
    int tx = tid & 15, ty = tid >> 4;
    long long row0 = (long long)blockIdx.y * 128;
    long long col0 = (long long)blockIdx.x * 128;
    float acc[8][8];
    #pragma unroll
    for (int i = 0; i < 8; ++i)
        #pragma unroll
        for (int j = 0; j < 8; ++j) acc[i][j] = 0.f;

    for (int d0 = 0; d0 < Dd; d0 += 16) {
        #pragma unroll
        for (int l = 0; l < 2; ++l) {
            int idx = l * 256 + tid;     // 0..511
            int r = idx >> 2;            // 0..127
            int dp = (idx & 3) * 4;      // 0,4,8,12
            float4 av = *(const float4*)(q + (row0 + r) * Dd + d0 + dp);
            As[dp + 0][r] = av.x; As[dp + 1][r] = av.y;
            As[dp + 2][r] = av.z; As[dp + 3][r] = av.w;
            float4 bv = *(const float4*)(key + (col0 + r) * Dd + d0 + dp);
            Bs[dp + 0][r] = bv.x; Bs[dp + 1][r] = bv.y;
            Bs[dp + 2][r] = bv.z; Bs[dp + 3][r] = bv.w;
        }
        __syncthreads();
        #pragma unroll
        for (int dd = 0; dd < 16; ++dd) {
            float a[8], b[8];
            *(float4*)&a[0] = *(const float4*)&As[dd][ty * 8];
            *(float4*)&a[4] = *(const float4*)&As[dd][ty * 8 + 4];
            *(float4*)&b[0] = *(const float4*)&Bs[dd][tx * 8];
            *(float4*)&b[4] = *(const float4*)&Bs[dd][tx * 8 + 4];
            #pragma unroll
            for (int i = 0; i < 8; ++i)
                #pragma unroll
                for (int j = 0; j < 8; ++j)
                    acc[i][j] = fmaf(a[i], b[j], acc[i][j]);
        }
        __syncthreads();
    }
    #pragma unroll
    for (int i = 0; i < 8; ++i) {
        long long r = row0 + ty * 8 + i;
        float4* dst = (float4*)(att + r * Mm + col0 + tx * 8);
        dst[0] = make_float4(acc[i][0], acc[i][1], acc[i][2], acc[i][3]);
        dst[1] = make_float4(acc[i][4], acc[i][5], acc[i][6], acc[i][7]);
    }
}

// ---------------- K4: per-row top-8 + softmax + outputs (att_w in place) ----------------
__global__ __launch_bounds__(256) void k_final(float* __restrict__ attw,
                                               const float* __restrict__ mem,
                                               const float* __restrict__ mlab,
                                               float* __restrict__ gate,
                                               float* __restrict__ memr,
                                               float* __restrict__ labr) {
    __shared__ float row[Mm];      // 16 KB
    __shared__ float rv[256];
    __shared__ int   ri[256];
    __shared__ float selp[KSEL];
    __shared__ int   seli[KSEL];
    __shared__ float selv[KSEL];
    int tid = threadIdx.x;
    long long r = blockIdx.x;
    float* arow = attw + r * Mm;

    for (int i = tid; i < Mm / 4; i += 256)
        ((float4*)row)[i] = ((const float4*)arow)[i];
    __syncthreads();

    // iterative argmax, lowest-index tie-break (matches lax.top_k)
    for (int k = 0; k < KSEL; ++k) {
        float bv = -INFINITY; int bi = Mm;
        for (int i = tid; i < Mm; i += 256) {
            float v = row[i];
            if (v > bv) { bv = v; bi = i; }     // strided ascending -> lowest i kept on ties
        }
        rv[tid] = bv; ri[tid] = bi;
        __syncthreads();
        #pragma unroll
        for (int s = 128; s > 0; s >>= 1) {
            if (tid < s) {
                float ov = rv[tid + s]; int oi = ri[tid + s];
                if (ov > rv[tid] || (ov == rv[tid] && oi < ri[tid])) { rv[tid] = ov; ri[tid] = oi; }
            }
            __syncthreads();
        }
        if (tid == 0) { selv[k] = rv[0]; seli[k] = ri[0]; row[ri[0]] = -INFINITY; }
        __syncthreads();
    }

    if (tid == 0) {
        float mx = selv[0];          // first extracted is the max
        float pp[KSEL]; float z = 0.f;
        #pragma unroll
        for (int k = 0; k < KSEL; ++k) { pp[k] = expf(selv[k] - mx); z += pp[k]; }
        float inv = 1.f / z;
        #pragma unroll
        for (int k = 0; k < KSEL; ++k) selp[k] = pp[k] * inv;
    }
    __syncthreads();

    // write att_w row: zeros with 8 sparse values (race-free, membership test)
    for (int i4 = tid; i4 < Mm / 4; i4 += 256) {
        float4 v = make_float4(0.f, 0.f, 0.f, 0.f);
        int base = i4 * 4;
        #pragma unroll
        for (int k = 0; k < KSEL; ++k) {
            int d = seli[k] - base;
            if ((unsigned)d < 4u) ((float*)&v)[d] = selp[k];
        }
        ((float4*)arow)[i4] = v;
    }

    // mem_retrieved row (256 floats)
    {
        float s = 0.f;
        #pragma unroll
        for (int k = 0; k < KSEL; ++k)
            s = fmaf(selp[k], mem[(long long)seli[k] * Dd + tid], s);
        memr[r * Dd + tid] = s;
    }
    // gate / label_retrieved row (8 floats, identical)
    if (tid < Ee) {
        float s = 0.f;
        #pragma unroll
        for (int k = 0; k < KSEL; ++k)
            s = fmaf(selp[k], mlab[(long long)seli[k] * Ee + tid], s);
        gate[r * Ee + tid] = s;
        labr[r * Ee + tid] = s;
    }
}

extern "C" void kernel_launch(void* const* d_in, const int* in_sizes, int n_in,
                              void* d_out, int out_size, void* d_ws, size_t ws_size,
                              hipStream_t stream) {
    const float* prop = (const float*)d_in[0];
    // d_in[1] = adap_embed (unused by reference)
    const float* W    = (const float*)d_in[2];
    const float* bias = (const float*)d_in[3];
    const float* key  = (const float*)d_in[4];
    const float* mem  = (const float*)d_in[5];
    const float* wg   = (const float*)d_in[6];
    // d_in[7] = w_noise (unused in eval mode)

    float* out  = (float*)d_out;
    float* gate = out + O_GATE;
    float* memr = out + O_MEMR;
    float* labr = out + O_LABR;
    float* mlab = out + O_MLAB;
    float* attw = out + O_ATTW;

    float* WT = (float*)d_ws;       // 256 KB scratch
    float* q  = memr;               // q lives in mem_retrieved region (dead before overwrite)

    k_transpose<<<256, 256, 0, stream>>>(W, WT);
    k_q<<<ROWS / 16, 256, 0, stream>>>(prop, WT, bias, q);
    k_mlabel<<<Mm / 256, 256, 0, stream>>>(mem, wg, mlab);
    dim3 g2(Mm / 128, ROWS / 128);
    k_att<<<g2, 256, 0, stream>>>(q, key, attw);
    k_final<<<ROWS, 256, 0, stream>>>(attw, mem, mlab, gate, memr, labr);
}

// Round 3
// 466.941 us; speedup vs baseline: 1.5072x; 1.5072x over previous
//
#include <hip/hip_runtime.h>
#include <hip/hip_fp16.h>
#include <math.h>

#define Bb 8
#define Tt 4
#define Nn 2048
#define Dd 256
#define Mm 4096
#define Ee 8
#define ROWS (Bb*Nn)   // 16384
#define KSEL 8
#define KC 16          // ranking candidates

// output offsets (floats)
#define O_GATE 0LL
#define O_MEMR 131072LL
#define O_LABR 4325376LL
#define O_MLAB 4456448LL
#define O_ATTW 4489216LL

// ws layout (bytes) — total 5.25 MB (proven available)
#define WS_WT    0LL            // 256 KB fp32 WT
#define WS_KH    262144LL       // 2 MB f16 key
#define WS_T8P   4456448LL      // 512 KB fp32 top8 probs
#define WS_T8I   4980736LL      // 512 KB int top8 idx

typedef float f32x4 __attribute__((ext_vector_type(4)));
typedef short short8 __attribute__((ext_vector_type(8)));
typedef _Float16 f16x8 __attribute__((ext_vector_type(8)));

__device__ __forceinline__ unsigned short f2h(float x) {
    __half h = __float2half(x);
    return *reinterpret_cast<unsigned short*>(&h);
}
__device__ __forceinline__ float h2f(unsigned short u) {
    __half h;
    *reinterpret_cast<unsigned short*>(&h) = u;
    return __half2float(h);
}

__device__ __forceinline__ void gload_lds16(const void* g, void* l) {
    __builtin_amdgcn_global_load_lds(
        (const __attribute__((address_space(1))) unsigned int*)g,
        (__attribute__((address_space(3))) unsigned int*)l,
        16, 0, 0);
}

// ---------------- K0: transpose W (256x256) into ws ----------------
__global__ void k_transpose(const float* __restrict__ W, float* __restrict__ WT) {
    int i = blockIdx.x * 256 + threadIdx.x;
    int r = i >> 8, c = i & 255;
    WT[c * 256 + r] = W[r * 256 + c];
}

// ---------------- K1: x = mean_T(prop); q = tanh(x @ W^T + b) -> f32 + f16 ----------------
__global__ __launch_bounds__(256) void k_q(const float* __restrict__ prop,
                                           const float* __restrict__ WT,
                                           const float* __restrict__ bias,
                                           float* __restrict__ qf,
                                           unsigned short* __restrict__ qh) {
    __shared__ float xs[16][256];
    int tid = threadIdx.x;
    int row0 = blockIdx.x * 16;
    #pragma unroll
    for (int r = 0; r < 16; ++r) {
        int row = row0 + r;
        int b = row >> 11;
        int n = row & 2047;
        const float* p = prop + ((long long)(b * Tt) * Nn + n) * Dd + tid;
        float s = 0.f;
        #pragma unroll
        for (int t = 0; t < Tt; ++t) s += p[(long long)t * Nn * Dd];
        xs[r][tid] = s * 0.25f;
    }
    __syncthreads();
    float acc[16];
    #pragma unroll
    for (int r = 0; r < 16; ++r) acc[r] = 0.f;
    int c = tid;
    for (int d = 0; d < 256; ++d) {
        float wv = WT[d * 256 + c];
        #pragma unroll
        for (int r = 0; r < 16; ++r) acc[r] = fmaf(xs[r][d], wv, acc[r]);
    }
    float bv = bias[c];
    #pragma unroll
    for (int r = 0; r < 16; ++r) {
        float qv = tanhf(acc[r] + bv);
        long long o = (long long)(row0 + r) * Dd + c;
        qf[o] = qv;
        qh[o] = f2h(qv);
    }
}

// ---------------- K1b: key -> f16 ----------------
__global__ void k_key16(const float* __restrict__ key, unsigned short* __restrict__ kh) {
    int idx = blockIdx.x * 256 + threadIdx.x;
    kh[idx] = f2h(key[idx]);
}

// ---------------- K2: mem_label = softmax(mem @ w_gate) ----------------
__global__ __launch_bounds__(256) void k_mlabel(const float* __restrict__ mem,
                                                const float* __restrict__ wg,
                                                float* __restrict__ mlab) {
    int m = blockIdx.x * 256 + threadIdx.x;
    if (m >= Mm) return;
    float acc[Ee];
    #pragma unroll
    for (int e = 0; e < Ee; ++e) acc[e] = 0.f;
    const float* mr = mem + (long long)m * Dd;
    for (int d = 0; d < Dd; ++d) {
        float mv = mr[d];
        #pragma unroll
        for (int e = 0; e < Ee; ++e) acc[e] = fmaf(mv, wg[d * Ee + e], acc[e]);
    }
    float mx = acc[0];
    #pragma unroll
    for (int e = 1; e < Ee; ++e) mx = fmaxf(mx, acc[e]);
    float z = 0.f;
    #pragma unroll
    for (int e = 0; e < Ee; ++e) { acc[e] = expf(acc[e] - mx); z += acc[e]; }
    float inv = 1.f / z;
    #pragma unroll
    for (int e = 0; e < Ee; ++e) mlab[(long long)m * Ee + e] = acc[e] * inv;
}

// ---------------- K3: att_f16 = q @ key^T, fp16 MFMA (ranking only) ----------------
__global__ __launch_bounds__(256) void k_att(const unsigned short* __restrict__ qh,
                                             const unsigned short* __restrict__ kh,
                                             unsigned short* __restrict__ attH) {
    __shared__ __align__(16) unsigned short smem[8192];  // A (8KB) | B (8KB)
    int tid = threadIdx.x;
    int lane = tid & 63, w = tid >> 6;
    int wr = w >> 1, wc = w & 1;
    long long row0 = (long long)blockIdx.y * 128;
    long long col0 = (long long)blockIdx.x * 128;

    f32x4 acc[4][4];
    #pragma unroll
    for (int m = 0; m < 4; ++m)
        #pragma unroll
        for (int n = 0; n < 4; ++n) acc[m][n] = (f32x4){0.f, 0.f, 0.f, 0.f};

    int rr = lane >> 2;       // 0..15
    int sp = lane & 3;        // physical slot this lane fills

    auto stage = [&](int k0) {
        #pragma unroll
        for (int t = 0; t < 2; ++t) {
            const unsigned short* src = t ? kh : qh;
            long long b0 = t ? col0 : row0;
            #pragma unroll
            for (int i = 0; i < 2; ++i) {
                int r = w * 32 + i * 16 + rr;
                int sl = sp ^ ((r >> 1) & 3);
                const unsigned short* g = src + (b0 + r) * 256 + k0 * 32 + sl * 8;
                unsigned short* l = smem + t * 4096 + (w * 32 + i * 16) * 32;
                gload_lds16(g, l);
            }
        }
    };

    stage(0);
    for (int k0 = 0; k0 < 8; ++k0) {
        __syncthreads();
        int lr = lane & 15, j = lane >> 4;
        f16x8 ah[4], bh[4];
        #pragma unroll
        for (int m = 0; m < 4; ++m) {
            int r = wr * 64 + m * 16 + lr;
            int off = r * 32 + ((j ^ ((r >> 1) & 3)) * 8);
            ah[m] = *(const f16x8*)(smem + off);
        }
        #pragma unroll
        for (int n = 0; n < 4; ++n) {
            int r = wc * 64 + n * 16 + lr;
            int off = r * 32 + ((j ^ ((r >> 1) & 3)) * 8);
            bh[n] = *(const f16x8*)(smem + 4096 + off);
        }
        #pragma unroll
        for (int m = 0; m < 4; ++m)
            #pragma unroll
            for (int n = 0; n < 4; ++n)
                acc[m][n] = __builtin_amdgcn_mfma_f32_16x16x32_f16(ah[m], bh[n], acc[m][n], 0, 0, 0);
        if (k0 < 7) { __syncthreads(); stage(k0 + 1); }
    }

    // C/D layout: col=lane&15, row=(lane>>4)*4+reg
    int lr = lane & 15, j = lane >> 4;
    #pragma unroll
    for (int m = 0; m < 4; ++m)
        #pragma unroll
        for (int n = 0; n < 4; ++n) {
            long long C = col0 + wc * 64 + n * 16 + lr;
            #pragma unroll
            for (int reg = 0; reg < 4; ++reg) {
                long long R = row0 + wr * 64 + m * 16 + j * 4 + reg;
                attH[R * Mm + C] = f2h(acc[m][n][reg]);
            }
        }
}

// ---------------- K4: rank top-16 (f16) -> refine fp64 -> top-8 + outputs ----------------
__device__ __forceinline__ bool gkey(float av, int ai, float bv, int bi) {
    return (av > bv) || (av == bv && ai < bi);
}

__global__ __launch_bounds__(256) void k_final2(const unsigned short* __restrict__ attH,
                                                const float* __restrict__ qf,
                                                const float* __restrict__ key,
                                                const float* __restrict__ mem,
                                                const float* __restrict__ mlab,
                                                float* __restrict__ gate,
                                                float* __restrict__ memr,
                                                float* __restrict__ labr,
                                                float* __restrict__ t8p,
                                                int* __restrict__ t8i) {
    int tid = threadIdx.x;
    int lane = tid & 63;
    long long row = (long long)blockIdx.x * 4 + (tid >> 6);
    const unsigned short* arow = attH + row * Mm;

    float v[KC]; int ix[KC];
    #pragma unroll
    for (int s = 0; s < KC; ++s) { v[s] = -INFINITY; ix[s] = 0x7FFFFFFF; }

    // per-lane scan of f16 att row (top-16 sorted insert, threshold fast path)
    #pragma unroll
    for (int t = 0; t < 8; ++t) {
        int c8 = t * 64 + lane;
        short8 x8 = *(const short8*)(arow + c8 * 8);
        #pragma unroll
        for (int jj = 0; jj < 8; ++jj) {
            float x = h2f((unsigned short)x8[jj]);
            int id = c8 * 8 + jj;
            if (gkey(x, id, v[KC - 1], ix[KC - 1])) {
                #pragma unroll
                for (int s = 0; s < KC; ++s) {
                    if (gkey(x, id, v[s], ix[s])) {
                        float tv = v[s]; int ti = ix[s];
                        v[s] = x; ix[s] = id; x = tv; id = ti;
                    }
                }
            }
        }
    }

    // butterfly merge across 64 lanes -> identical top-16 everywhere
    #pragma unroll
    for (int d = 1; d < 64; d <<= 1) {
        float pv[KC]; int pi[KC];
        #pragma unroll
        for (int s = 0; s < KC; ++s) {
            pv[s] = __shfl_xor(v[s], d);
            pi[s] = __shfl_xor(ix[s], d);
        }
        float nv[KC]; int ni[KC];
        #pragma unroll
        for (int s = 0; s < KC; ++s) {
            bool g = gkey(pv[KC - 1 - s], pi[KC - 1 - s], v[s], ix[s]);
            nv[s] = g ? pv[KC - 1 - s] : v[s];
            ni[s] = g ? pi[KC - 1 - s] : ix[s];
        }
        #pragma unroll
        for (int st = 8; st >= 1; st >>= 1) {
            #pragma unroll
            for (int a = 0; a < KC; ++a) {
                if ((a & st) == 0 && a + st < KC) {
                    int b2 = a + st;
                    bool g = gkey(nv[b2], ni[b2], nv[a], ni[a]);
                    if (g) {
                        float tv = nv[a]; int ti = ni[a];
                        nv[a] = nv[b2]; ni[a] = ni[b2];
                        nv[b2] = tv; ni[b2] = ti;
                    }
                }
            }
        }
        #pragma unroll
        for (int s = 0; s < KC; ++s) { v[s] = nv[s]; ix[s] = ni[s]; }
    }

    // refine: candidate c = lane&15, d-slice g = lane>>4 (64 elems), fp64 accumulate
    int c = lane & 15, g = lane >> 4;
    int cidx = 0;
    #pragma unroll
    for (int s = 0; s < KC; ++s) if (c == s) cidx = ix[s];
    const float* qrow = qf + row * Dd;      // fp32 q lives in memr region (own row only)
    const float* krow = key + (long long)cidx * Dd;
    double dacc = 0.0;
    #pragma unroll
    for (int i = 0; i < 16; ++i) {
        float4 qv = *(const float4*)(qrow + g * 64 + i * 4);
        float4 kv = *(const float4*)(krow + g * 64 + i * 4);
        dacc = fma((double)qv.x, (double)kv.x, dacc);
        dacc = fma((double)qv.y, (double)kv.y, dacc);
        dacc = fma((double)qv.z, (double)kv.z, dacc);
        dacc = fma((double)qv.w, (double)kv.w, dacc);
    }
    dacc += __shfl_xor(dacc, 16);
    dacc += __shfl_xor(dacc, 32);
    float rvf = (float)dacc;
    float cv[KC];
    #pragma unroll
    for (int s = 0; s < KC; ++s) cv[s] = __shfl(rvf, s);

    // top-8 of the 16 refined (val desc, idx asc), static indexing only
    float sv[KSEL]; int si[KSEL];
    #pragma unroll
    for (int k = 0; k < KSEL; ++k) {
        float bv = -INFINITY; int bi = 0x7FFFFFFF;
        #pragma unroll
        for (int s = 0; s < KC; ++s)
            if (gkey(cv[s], ix[s], bv, bi)) { bv = cv[s]; bi = ix[s]; }
        sv[k] = bv; si[k] = bi;
        #pragma unroll
        for (int s = 0; s < KC; ++s)
            if (cv[s] == bv && ix[s] == bi) { cv[s] = -INFINITY; ix[s] = 0x7FFFFFFF; }
    }

    // softmax over 8 (sv[0] is max)
    float p[KSEL]; float z = 0.f;
    #pragma unroll
    for (int s = 0; s < KSEL; ++s) { p[s] = expf(sv[s] - sv[0]); z += p[s]; }
    float inv = 1.f / z;
    #pragma unroll
    for (int s = 0; s < KSEL; ++s) p[s] *= inv;

    // mem_retrieved (overwrites q row — already fully read above)
    {
        float4 a = make_float4(0.f, 0.f, 0.f, 0.f);
        #pragma unroll
        for (int s = 0; s < KSEL; ++s) {
            const float4 mv = *(const float4*)(mem + (long long)si[s] * Dd + lane * 4);
            a.x = fmaf(p[s], mv.x, a.x); a.y = fmaf(p[s], mv.y, a.y);
            a.z = fmaf(p[s], mv.z, a.z); a.w = fmaf(p[s], mv.w, a.w);
        }
        *(float4*)(memr + row * Dd + lane * 4) = a;
    }

    float myp = 0.f; int myi = 0;
    #pragma unroll
    for (int s = 0; s < KSEL; ++s) if ((lane & 7) == s) { myp = p[s]; myi = si[s]; }
    if (lane < Ee) {
        float s8 = 0.f;
        #pragma unroll
        for (int s = 0; s < KSEL; ++s)
            s8 = fmaf(p[s], mlab[(long long)si[s] * Ee + lane], s8);
        gate[row * Ee + lane] = s8;
        labr[row * Ee + lane] = s8;
        t8p[row * KSEL + lane] = myp;
        t8i[row * KSEL + lane] = myi;
    }
}

// ---------------- K5: fused zero + sparse insert for att_w ----------------
__global__ __launch_bounds__(256) void k_attw(const float* __restrict__ t8p,
                                              const int* __restrict__ t8i,
                                              float* __restrict__ attw) {
    int tid = threadIdx.x, lane = tid & 63;
    long long row = (long long)blockIdx.x * 4 + (tid >> 6);
    float lp = 0.f; int li = -1;
    if (lane < 8) { lp = t8p[row * KSEL + lane]; li = t8i[row * KSEL + lane]; }
    float ps[8]; int is[8];
    #pragma unroll
    for (int s = 0; s < 8; ++s) { ps[s] = __shfl(lp, s); is[s] = __shfl(li, s); }
    float* arow = attw + row * Mm;
    #pragma unroll
    for (int t = 0; t < 16; ++t) {
        int base = (t * 64 + lane) * 4;
        float4 vv = make_float4(0.f, 0.f, 0.f, 0.f);
        bool any = false;
        #pragma unroll
        for (int s = 0; s < 8; ++s) any |= ((unsigned)(is[s] - base) < 4u);
        if (any) {
            #pragma unroll
            for (int s = 0; s < 8; ++s) {
                vv.x = (is[s] == base + 0) ? ps[s] : vv.x;
                vv.y = (is[s] == base + 1) ? ps[s] : vv.y;
                vv.z = (is[s] == base + 2) ? ps[s] : vv.z;
                vv.w = (is[s] == base + 3) ? ps[s] : vv.w;
            }
        }
        *(float4*)(arow + base) = vv;
    }
}

extern "C" void kernel_launch(void* const* d_in, const int* in_sizes, int n_in,
                              void* d_out, int out_size, void* d_ws, size_t ws_size,
                              hipStream_t stream) {
    const float* prop = (const float*)d_in[0];
    const float* W    = (const float*)d_in[2];
    const float* bias = (const float*)d_in[3];
    const float* key  = (const float*)d_in[4];
    const float* mem  = (const float*)d_in[5];
    const float* wg   = (const float*)d_in[6];

    float* out  = (float*)d_out;
    float* gate = out + O_GATE;
    float* memr = out + O_MEMR;
    float* labr = out + O_LABR;
    float* mlab = out + O_MLAB;
    float* attw = out + O_ATTW;

    char* ws = (char*)d_ws;
    float*          WT  = (float*)(ws + WS_WT);
    unsigned short* kh  = (unsigned short*)(ws + WS_KH);
    float*          t8p = (float*)(ws + WS_T8P);
    int*            t8i = (int*)(ws + WS_T8I);

    // f16 att in first 128 MB of attw region; f16 q at +128 MB; f32 q in memr region
    unsigned short* attH = (unsigned short*)attw;
    unsigned short* qh   = attH + (long long)ROWS * Mm;
    float*          qf   = memr;

    k_transpose<<<256, 256, 0, stream>>>(W, WT);
    k_q<<<ROWS / 16, 256, 0, stream>>>(prop, WT, bias, qf, qh);
    k_key16<<<(Mm * Dd) / 256, 256, 0, stream>>>(key, kh);
    k_mlabel<<<Mm / 256, 256, 0, stream>>>(mem, wg, mlab);
    dim3 g2(Mm / 128, ROWS / 128);
    k_att<<<g2, 256, 0, stream>>>(qh, kh, attH);
    k_final2<<<ROWS / 4, 256, 0, stream>>>(attH, qf, key, mem, mlab, gate, memr, labr, t8p, t8i);
    k_attw<<<ROWS / 4, 256, 0, stream>>>(t8p, t8i, attw);
}

// Round 4
// 307.305 us; speedup vs baseline: 2.2902x; 1.5195x over previous
//
#include <hip/hip_runtime.h>
#include <hip/hip_fp16.h>
#include <math.h>

#define Bb 8
#define Tt 4
#define Nn 2048
#define Dd 256
#define Mm 4096
#define Ee 8
#define ROWS (Bb*Nn)   // 16384
#define KSEL 8
#define KC 16          // ranking candidates

// output offsets (floats)
#define O_GATE 0LL
#define O_MEMR 131072LL
#define O_LABR 4325376LL
#define O_MLAB 4456448LL
#define O_ATTW 4489216LL

// ws layout (bytes) — total 4.25 MB
#define WS_WT    0LL            // 256 KB fp32 WT
#define WS_KH    262144LL       // 2 MB f16 key
#define WS_T16P  2359296LL      // 1 MB fp32 cand probs (16/row)
#define WS_T16I  3407872LL      // 1 MB int cand idx (16/row)

typedef float f32x4 __attribute__((ext_vector_type(4)));
typedef short short8 __attribute__((ext_vector_type(8)));
typedef _Float16 f16x8 __attribute__((ext_vector_type(8)));

__device__ __forceinline__ unsigned short f2h(float x) {
    __half h = __float2half(x);
    return *reinterpret_cast<unsigned short*>(&h);
}

__device__ __forceinline__ void gload_lds16(const void* g, void* l) {
    __builtin_amdgcn_global_load_lds(
        (const __attribute__((address_space(1))) unsigned int*)g,
        (__attribute__((address_space(3))) unsigned int*)l,
        16, 0, 0);
}

// ---------------- K0: transpose W (256x256) into ws ----------------
__global__ void k_transpose(const float* __restrict__ W, float* __restrict__ WT) {
    int i = blockIdx.x * 256 + threadIdx.x;
    int r = i >> 8, c = i & 255;
    WT[c * 256 + r] = W[r * 256 + c];
}

// ---------------- K1: x = mean_T(prop); q = tanh(x @ W^T + b) -> f32 + f16 ----------------
__global__ __launch_bounds__(256) void k_q(const float* __restrict__ prop,
                                           const float* __restrict__ WT,
                                           const float* __restrict__ bias,
                                           float* __restrict__ qf,
                                           unsigned short* __restrict__ qh) {
    __shared__ float xs[16][256];
    int tid = threadIdx.x;
    int row0 = blockIdx.x * 16;
    #pragma unroll
    for (int r = 0; r < 16; ++r) {
        int row = row0 + r;
        int b = row >> 11;
        int n = row & 2047;
        const float* p = prop + ((long long)(b * Tt) * Nn + n) * Dd + tid;
        float s = 0.f;
        #pragma unroll
        for (int t = 0; t < Tt; ++t) s += p[(long long)t * Nn * Dd];
        xs[r][tid] = s * 0.25f;
    }
    __syncthreads();
    float acc[16];
    #pragma unroll
    for (int r = 0; r < 16; ++r) acc[r] = 0.f;
    int c = tid;
    for (int d = 0; d < 256; ++d) {
        float wv = WT[d * 256 + c];
        #pragma unroll
        for (int r = 0; r < 16; ++r) acc[r] = fmaf(xs[r][d], wv, acc[r]);
    }
    float bv = bias[c];
    #pragma unroll
    for (int r = 0; r < 16; ++r) {
        float qv = tanhf(acc[r] + bv);
        long long o = (long long)(row0 + r) * Dd + c;
        qf[o] = qv;
        qh[o] = f2h(qv);
    }
}

// ---------------- K1b: key -> f16 ----------------
__global__ void k_key16(const float* __restrict__ key, unsigned short* __restrict__ kh) {
    int idx = blockIdx.x * 256 + threadIdx.x;
    kh[idx] = f2h(key[idx]);
}

// ---------------- K2: mem_label = softmax(mem @ w_gate) ----------------
__global__ __launch_bounds__(256) void k_mlabel(const float* __restrict__ mem,
                                                const float* __restrict__ wg,
                                                float* __restrict__ mlab) {
    int m = blockIdx.x * 256 + threadIdx.x;
    if (m >= Mm) return;
    float acc[Ee];
    #pragma unroll
    for (int e = 0; e < Ee; ++e) acc[e] = 0.f;
    const float* mr = mem + (long long)m * Dd;
    for (int d = 0; d < Dd; ++d) {
        float mv = mr[d];
        #pragma unroll
        for (int e = 0; e < Ee; ++e) acc[e] = fmaf(mv, wg[d * Ee + e], acc[e]);
    }
    float mx = acc[0];
    #pragma unroll
    for (int e = 1; e < Ee; ++e) mx = fmaxf(mx, acc[e]);
    float z = 0.f;
    #pragma unroll
    for (int e = 0; e < Ee; ++e) { acc[e] = expf(acc[e] - mx); z += acc[e]; }
    float inv = 1.f / z;
    #pragma unroll
    for (int e = 0; e < Ee; ++e) mlab[(long long)m * Ee + e] = acc[e] * inv;
}

// ---------------- K3: att_f16 = q @ key^T, fp16 MFMA (ranking only) ----------------
__global__ __launch_bounds__(256) void k_att(const unsigned short* __restrict__ qh,
                                             const unsigned short* __restrict__ kh,
                                             unsigned short* __restrict__ attH) {
    __shared__ __align__(16) unsigned short smem[8192];  // A (8KB) | B (8KB)
    int tid = threadIdx.x;
    int lane = tid & 63, w = tid >> 6;
    int wr = w >> 1, wc = w & 1;
    long long row0 = (long long)blockIdx.y * 128;
    long long col0 = (long long)blockIdx.x * 128;

    f32x4 acc[4][4];
    #pragma unroll
    for (int m = 0; m < 4; ++m)
        #pragma unroll
        for (int n = 0; n < 4; ++n) acc[m][n] = (f32x4){0.f, 0.f, 0.f, 0.f};

    int rr = lane >> 2;
    int sp = lane & 3;

    auto stage = [&](int k0) {
        #pragma unroll
        for (int t = 0; t < 2; ++t) {
            const unsigned short* src = t ? kh : qh;
            long long b0 = t ? col0 : row0;
            #pragma unroll
            for (int i = 0; i < 2; ++i) {
                int r = w * 32 + i * 16 + rr;
                int sl = sp ^ ((r >> 1) & 3);
                const unsigned short* g = src + (b0 + r) * 256 + k0 * 32 + sl * 8;
                unsigned short* l = smem + t * 4096 + (w * 32 + i * 16) * 32;
                gload_lds16(g, l);
            }
        }
    };

    stage(0);
    for (int k0 = 0; k0 < 8; ++k0) {
        __syncthreads();
        int lr = lane & 15, j = lane >> 4;
        f16x8 ah[4], bh[4];
        #pragma unroll
        for (int m = 0; m < 4; ++m) {
            int r = wr * 64 + m * 16 + lr;
            int off = r * 32 + ((j ^ ((r >> 1) & 3)) * 8);
            ah[m] = *(const f16x8*)(smem + off);
        }
        #pragma unroll
        for (int n = 0; n < 4; ++n) {
            int r = wc * 64 + n * 16 + lr;
            int off = r * 32 + ((j ^ ((r >> 1) & 3)) * 8);
            bh[n] = *(const f16x8*)(smem + 4096 + off);
        }
        #pragma unroll
        for (int m = 0; m < 4; ++m)
            #pragma unroll
            for (int n = 0; n < 4; ++n)
                acc[m][n] = __builtin_amdgcn_mfma_f32_16x16x32_f16(ah[m], bh[n], acc[m][n], 0, 0, 0);
        if (k0 < 7) { __syncthreads(); stage(k0 + 1); }
    }

    int lr = lane & 15, j = lane >> 4;
    #pragma unroll
    for (int m = 0; m < 4; ++m)
        #pragma unroll
        for (int n = 0; n < 4; ++n) {
            long long C = col0 + wc * 64 + n * 16 + lr;
            #pragma unroll
            for (int reg = 0; reg < 4; ++reg) {
                long long R = row0 + wr * 64 + m * 16 + j * 4 + reg;
                attH[R * Mm + C] = f2h(acc[m][n][reg]);
            }
        }
}

// ---------------- K4: packed-key top-16 -> fp64 refine -> top-8 + outputs ----------------
__global__ __launch_bounds__(256) void k_final2(const unsigned short* __restrict__ attH,
                                                const float* __restrict__ qf,
                                                const float* __restrict__ key,
                                                const float* __restrict__ mem,
                                                const float* __restrict__ mlab,
                                                float* __restrict__ gate,
                                                float* __restrict__ memr,
                                                float* __restrict__ labr,
                                                float* __restrict__ t16p,
                                                int* __restrict__ t16i) {
    int tid = threadIdx.x;
    int lane = tid & 63;
    long long row = (long long)blockIdx.x * 4 + (tid >> 6);
    const unsigned short* arow = attH + row * Mm;

    // ---- per-lane top-8 packed keys: key = mono16(f16)<<16 | (4095-idx) ----
    unsigned int v[8];
    #pragma unroll
    for (int s = 0; s < 8; ++s) v[s] = 0u;

    #pragma unroll
    for (int t = 0; t < 8; ++t) {
        int c8 = t * 64 + lane;
        short8 x8 = *(const short8*)(arow + c8 * 8);
        unsigned int rb = (unsigned)(4095 - c8 * 8);
        #pragma unroll
        for (int jj = 0; jj < 8; ++jj) {
            unsigned int b = (unsigned short)x8[jj];
            unsigned int sr = (unsigned)((int)(b << 16) >> 31);    // 0 or all-ones
            unsigned int mono = b ^ ((sr >> 17) | 0x8000u);        // order-preserving
            unsigned int keyv = (mono << 16) | (rb - jj);
            if (keyv > v[7]) {
                unsigned int x = keyv;
                #pragma unroll
                for (int s = 0; s < 8; ++s) {
                    unsigned int hi = v[s] > x ? v[s] : x;
                    unsigned int lo = v[s] > x ? x : v[s];
                    v[s] = hi; x = lo;
                }
            }
        }
    }

    // ---- extract global top-16 via wave-max pops ----
    unsigned int sk[KC];
    #pragma unroll
    for (int k = 0; k < KC; ++k) {
        unsigned int bv = v[0];
        #pragma unroll
        for (int d = 1; d < 64; d <<= 1) {
            unsigned int ov = (unsigned)__shfl_xor((int)bv, d);
            bv = bv > ov ? bv : ov;
        }
        sk[k] = bv;
        bool won = (v[0] == bv);
        #pragma unroll
        for (int s = 0; s < 7; ++s) v[s] = won ? v[s + 1] : v[s];
        v[7] = won ? 0u : v[7];
    }

    int civ[KC];
    #pragma unroll
    for (int s = 0; s < KC; ++s) civ[s] = 4095 - (int)(sk[s] & 0xFFFFu);

    // ---- refine: candidate c = lane&15, slice g = lane>>4, fp64 dot ----
    int c = lane & 15, g = lane >> 4;
    int cidx = civ[0];
    #pragma unroll
    for (int s = 1; s < KC; ++s) cidx = (c == s) ? civ[s] : cidx;
    const float* qrow = qf + row * Dd;
    const float* krow = key + (long long)cidx * Dd;
    double dacc = 0.0;
    #pragma unroll
    for (int i = 0; i < 16; ++i) {
        float4 qv = *(const float4*)(qrow + g * 64 + i * 4);
        float4 kv = *(const float4*)(krow + g * 64 + i * 4);
        dacc = fma((double)qv.x, (double)kv.x, dacc);
        dacc = fma((double)qv.y, (double)kv.y, dacc);
        dacc = fma((double)qv.z, (double)kv.z, dacc);
        dacc = fma((double)qv.w, (double)kv.w, dacc);
    }
    dacc += __shfl_xor(dacc, 16);
    dacc += __shfl_xor(dacc, 32);
    float rvf = (float)dacc;

    float cv[KC];
    #pragma unroll
    for (int s = 0; s < KC; ++s) cv[s] = __shfl(rvf, s);

    // ---- all-pairs rank on (refined value desc, idx asc); selected = rank<8 ----
    unsigned int m32[KC];
    #pragma unroll
    for (int s = 0; s < KC; ++s) {
        unsigned int fb = __float_as_uint(cv[s]);
        m32[s] = fb ^ ((unsigned)((int)fb >> 31) | 0x80000000u);
    }
    bool sel[KC];
    #pragma unroll
    for (int s = 0; s < KC; ++s) {
        int r = 0;
        #pragma unroll
        for (int t = 0; t < KC; ++t) {
            if (t != s) {
                bool gt = (m32[t] > m32[s]) || (m32[t] == m32[s] && civ[t] < civ[s]);
                r += gt ? 1 : 0;
            }
        }
        sel[s] = (r < KSEL);
    }

    // ---- softmax over selected (max is global max since top-1 always selected) ----
    float mx = cv[0];
    #pragma unroll
    for (int s = 1; s < KC; ++s) mx = fmaxf(mx, cv[s]);
    float p[KC]; float z = 0.f;
    #pragma unroll
    for (int s = 0; s < KC; ++s) { p[s] = sel[s] ? expf(cv[s] - mx) : 0.f; z += p[s]; }
    float inv = 1.f / z;
    #pragma unroll
    for (int s = 0; s < KC; ++s) p[s] *= inv;

    // ---- mem_retrieved (reads mem rows, overwrites q row after full read) ----
    {
        float4 a = make_float4(0.f, 0.f, 0.f, 0.f);
        #pragma unroll
        for (int s = 0; s < KC; ++s) {
            if (sel[s]) {
                const float4 mv = *(const float4*)(mem + (long long)civ[s] * Dd + lane * 4);
                a.x = fmaf(p[s], mv.x, a.x); a.y = fmaf(p[s], mv.y, a.y);
                a.z = fmaf(p[s], mv.z, a.z); a.w = fmaf(p[s], mv.w, a.w);
            }
        }
        *(float4*)(memr + row * Dd + lane * 4) = a;
    }

    if (lane < Ee) {
        float s8 = 0.f;
        #pragma unroll
        for (int s = 0; s < KC; ++s)
            if (sel[s]) s8 = fmaf(p[s], mlab[(long long)civ[s] * Ee + lane], s8);
        gate[row * Ee + lane] = s8;
        labr[row * Ee + lane] = s8;
    }
    if (lane < KC) {
        float myp = p[0]; int myi = civ[0];
        #pragma unroll
        for (int s = 1; s < KC; ++s) {
            myp = (lane == s) ? p[s] : myp;
            myi = (lane == s) ? civ[s] : myi;
        }
        t16p[row * KC + lane] = myp;
        t16i[row * KC + lane] = myi;
    }
}

// ---------------- K5: zero row + sparse insert (16 vals, 8 nonzero) ----------------
__global__ __launch_bounds__(256) void k_attw(const float* __restrict__ t16p,
                                              const int* __restrict__ t16i,
                                              float* __restrict__ attw) {
    int tid = threadIdx.x, lane = tid & 63;
    long long row = (long long)blockIdx.x * 4 + (tid >> 6);
    float* arow = attw + row * Mm;
    float4 zz = make_float4(0.f, 0.f, 0.f, 0.f);
    #pragma unroll
    for (int t = 0; t < 16; ++t)
        *(float4*)(arow + (t * 64 + lane) * 4) = zz;
    __syncthreads();   // drain zero-stores before sparse inserts (cross-lane same-addr)
    if (lane < KC) {
        float pv = t16p[row * KC + lane];
        int iv = t16i[row * KC + lane];
        arow[iv] = pv;   // unselected write 0.0 at their own idx: true value there is 0.0
    }
}

extern "C" void kernel_launch(void* const* d_in, const int* in_sizes, int n_in,
                              void* d_out, int out_size, void* d_ws, size_t ws_size,
                              hipStream_t stream) {
    const float* prop = (const float*)d_in[0];
    const float* W    = (const float*)d_in[2];
    const float* bias = (const float*)d_in[3];
    const float* key  = (const float*)d_in[4];
    const float* mem  = (const float*)d_in[5];
    const float* wg   = (const float*)d_in[6];

    float* out  = (float*)d_out;
    float* gate = out + O_GATE;
    float* memr = out + O_MEMR;
    float* labr = out + O_LABR;
    float* mlab = out + O_MLAB;
    float* attw = out + O_ATTW;

    char* ws = (char*)d_ws;
    float*          WT   = (float*)(ws + WS_WT);
    unsigned short* kh   = (unsigned short*)(ws + WS_KH);
    float*          t16p = (float*)(ws + WS_T16P);
    int*            t16i = (int*)(ws + WS_T16I);

    // f16 att in first 128 MB of attw region; f16 q at +128 MB; f32 q in memr region
    unsigned short* attH = (unsigned short*)attw;
    unsigned short* qh   = attH + (long long)ROWS * Mm;
    float*          qf   = memr;

    k_transpose<<<256, 256, 0, stream>>>(W, WT);
    k_q<<<ROWS / 16, 256, 0, stream>>>(prop, WT, bias, qf, qh);
    k_key16<<<(Mm * Dd) / 256, 256, 0, stream>>>(key, kh);
    k_mlabel<<<Mm / 256, 256, 0, stream>>>(mem, wg, mlab);
    dim3 g2(Mm / 128, ROWS / 128);
    k_att<<<g2, 256, 0, stream>>>(qh, kh, attH);
    k_final2<<<ROWS / 4, 256, 0, stream>>>(attH, qf, key, mem, mlab, gate, memr, labr, t16p, t16i);
    k_attw<<<ROWS / 4, 256, 0, stream>>>(t16p, t16i, attw);
}

// Round 6
// 276.276 us; speedup vs baseline: 2.5474x; 1.1123x over previous
//
#include <hip/hip_runtime.h>
#include <hip/hip_fp16.h>
#include <math.h>

#define Bb 8
#define Tt 4
#define Nn 2048
#define Dd 256
#define Mm 4096
#define Ee 8
#define ROWS (Bb*Nn)   // 16384
#define KSEL 8
#define KC 16          // ranking candidates

// output offsets (floats)
#define O_GATE 0LL
#define O_MEMR 131072LL
#define O_LABR 4325376LL
#define O_MLAB 4456448LL
#define O_ATTW 4489216LL

// ws layout (bytes) — ~159 MB used; ws evidenced ≈1.1 GB (0xAA fill dispatch = 1.146 GB)
#define WS_WT    0LL            // 256 KB fp32 WT
#define WS_KH    262144LL       // 2 MB f16 key
#define WS_ATTH  16777216LL     // 128 MB f16 att (16384 x 4096)
#define WS_QH    150994944LL    // 8 MB f16 q

typedef float f32x4 __attribute__((ext_vector_type(4)));
typedef short short8 __attribute__((ext_vector_type(8)));
typedef _Float16 f16x8 __attribute__((ext_vector_type(8)));

__device__ __forceinline__ unsigned short f2h(float x) {
    __half h = __float2half(x);
    return *reinterpret_cast<unsigned short*>(&h);
}

__device__ __forceinline__ void gload_lds16(const void* g, void* l) {
    __builtin_amdgcn_global_load_lds(
        (const __attribute__((address_space(1))) unsigned int*)g,
        (__attribute__((address_space(3))) unsigned int*)l,
        16, 0, 0);
}

// ---------------- K0: transpose W (256x256) into ws ----------------
__global__ void k_transpose(const float* __restrict__ W, float* __restrict__ WT) {
    int i = blockIdx.x * 256 + threadIdx.x;
    int r = i >> 8, c = i & 255;
    WT[c * 256 + r] = W[r * 256 + c];
}

// ---------------- K1: x = mean_T(prop); q = tanh(x @ W^T + b) -> f32 + f16 ----------------
__global__ __launch_bounds__(256) void k_q(const float* __restrict__ prop,
                                           const float* __restrict__ WT,
                                           const float* __restrict__ bias,
                                           float* __restrict__ qf,
                                           unsigned short* __restrict__ qh) {
    __shared__ float xs[16][256];
    int tid = threadIdx.x;
    int row0 = blockIdx.x * 16;
    #pragma unroll
    for (int r = 0; r < 16; ++r) {
        int row = row0 + r;
        int b = row >> 11;
        int n = row & 2047;
        const float* p = prop + ((long long)(b * Tt) * Nn + n) * Dd + tid;
        float s = 0.f;
        #pragma unroll
        for (int t = 0; t < Tt; ++t) s += p[(long long)t * Nn * Dd];
        xs[r][tid] = s * 0.25f;
    }
    __syncthreads();
    float acc[16];
    #pragma unroll
    for (int r = 0; r < 16; ++r) acc[r] = 0.f;
    int c = tid;
    for (int d = 0; d < 256; ++d) {
        float wv = WT[d * 256 + c];
        #pragma unroll
        for (int r = 0; r < 16; ++r) acc[r] = fmaf(xs[r][d], wv, acc[r]);
    }
    float bv = bias[c];
    #pragma unroll
    for (int r = 0; r < 16; ++r) {
        float qv = tanhf(acc[r] + bv);
        long long o = (long long)(row0 + r) * Dd + c;
        qf[o] = qv;
        qh[o] = f2h(qv);
    }
}

// ---------------- K1b: key -> f16 ----------------
__global__ void k_key16(const float* __restrict__ key, unsigned short* __restrict__ kh) {
    int idx = blockIdx.x * 256 + threadIdx.x;
    kh[idx] = f2h(key[idx]);
}

// ---------------- K2: mem_label = softmax(mem @ w_gate) ----------------
__global__ __launch_bounds__(256) void k_mlabel(const float* __restrict__ mem,
                                                const float* __restrict__ wg,
                                                float* __restrict__ mlab) {
    int m = blockIdx.x * 256 + threadIdx.x;
    if (m >= Mm) return;
    float acc[Ee];
    #pragma unroll
    for (int e = 0; e < Ee; ++e) acc[e] = 0.f;
    const float* mr = mem + (long long)m * Dd;
    for (int d = 0; d < Dd; ++d) {
        float mv = mr[d];
        #pragma unroll
        for (int e = 0; e < Ee; ++e) acc[e] = fmaf(mv, wg[d * Ee + e], acc[e]);
    }
    float mx = acc[0];
    #pragma unroll
    for (int e = 1; e < Ee; ++e) mx = fmaxf(mx, acc[e]);
    float z = 0.f;
    #pragma unroll
    for (int e = 0; e < Ee; ++e) { acc[e] = expf(acc[e] - mx); z += acc[e]; }
    float inv = 1.f / z;
    #pragma unroll
    for (int e = 0; e < Ee; ++e) mlab[(long long)m * Ee + e] = acc[e] * inv;
}

// ---------------- K3: att_f16 = q @ key^T, fp16 MFMA (ranking only) ----------------
// 1D grid of 4096 blocks, bijective XCD swizzle (4096 % 8 == 0)
__global__ __launch_bounds__(256) void k_att(const unsigned short* __restrict__ qh,
                                             const unsigned short* __restrict__ kh,
                                             unsigned short* __restrict__ attH) {
    __shared__ __align__(16) unsigned short smem[8192];  // A (8KB) | B (8KB)
    int bid = blockIdx.x;
    int swz = (bid & 7) * 512 + (bid >> 3);     // XCD-contiguous chunks
    int bx = swz & 31;                          // col tile 0..31
    int by = swz >> 5;                          // row tile 0..127
    int tid = threadIdx.x;
    int lane = tid & 63, w = tid >> 6;
    int wr = w >> 1, wc = w & 1;
    long long row0 = (long long)by * 128;
    long long col0 = (long long)bx * 128;

    f32x4 acc[4][4];
    #pragma unroll
    for (int m = 0; m < 4; ++m)
        #pragma unroll
        for (int n = 0; n < 4; ++n) acc[m][n] = (f32x4){0.f, 0.f, 0.f, 0.f};

    int rr = lane >> 2;
    int sp = lane & 3;

    auto stage = [&](int k0) {
        #pragma unroll
        for (int t = 0; t < 2; ++t) {
            const unsigned short* src = t ? kh : qh;
            long long b0 = t ? col0 : row0;
            #pragma unroll
            for (int i = 0; i < 2; ++i) {
                int r = w * 32 + i * 16 + rr;
                int sl = sp ^ ((r >> 1) & 3);
                const unsigned short* g = src + (b0 + r) * 256 + k0 * 32 + sl * 8;
                unsigned short* l = smem + t * 4096 + (w * 32 + i * 16) * 32;
                gload_lds16(g, l);
            }
        }
    };

    stage(0);
    for (int k0 = 0; k0 < 8; ++k0) {
        __syncthreads();
        int lr = lane & 15, j = lane >> 4;
        f16x8 ah[4], bh[4];
        #pragma unroll
        for (int m = 0; m < 4; ++m) {
            int r = wr * 64 + m * 16 + lr;
            int off = r * 32 + ((j ^ ((r >> 1) & 3)) * 8);
            ah[m] = *(const f16x8*)(smem + off);
        }
        #pragma unroll
        for (int n = 0; n < 4; ++n) {
            int r = wc * 64 + n * 16 + lr;
            int off = r * 32 + ((j ^ ((r >> 1) & 3)) * 8);
            bh[n] = *(const f16x8*)(smem + 4096 + off);
        }
        #pragma unroll
        for (int m = 0; m < 4; ++m)
            #pragma unroll
            for (int n = 0; n < 4; ++n)
                acc[m][n] = __builtin_amdgcn_mfma_f32_16x16x32_f16(ah[m], bh[n], acc[m][n], 0, 0, 0);
        if (k0 < 7) { __syncthreads(); stage(k0 + 1); }
    }

    int lr = lane & 15, j = lane >> 4;
    #pragma unroll
    for (int m = 0; m < 4; ++m)
        #pragma unroll
        for (int n = 0; n < 4; ++n) {
            long long C = col0 + wc * 64 + n * 16 + lr;
            #pragma unroll
            for (int reg = 0; reg < 4; ++reg) {
                long long R = row0 + wr * 64 + m * 16 + j * 4 + reg;
                attH[R * Mm + C] = f2h(acc[m][n][reg]);
            }
        }
}

// ---------------- K4: top-16 rank -> fp64 refine -> top-8 + ALL outputs (attw fused) ----------------
__global__ __launch_bounds__(256) void k_final2(const unsigned short* __restrict__ attH,
                                                const float* __restrict__ qf,
                                                const float* __restrict__ key,
                                                const float* __restrict__ mem,
                                                const float* __restrict__ mlab,
                                                float* __restrict__ gate,
                                                float* __restrict__ memr,
                                                float* __restrict__ labr,
                                                float* __restrict__ attw) {
    int tid = threadIdx.x;
    int lane = tid & 63;
    long long row = (long long)blockIdx.x * 4 + (tid >> 6);
    const unsigned short* arow = attH + row * Mm;

    // ---- per-lane top-8 packed keys: key = mono16(f16)<<16 | (4095-idx) ----
    unsigned int v[8];
    #pragma unroll
    for (int s = 0; s < 8; ++s) v[s] = 0u;

    #pragma unroll
    for (int t = 0; t < 8; ++t) {
        int c8 = t * 64 + lane;
        short8 x8 = *(const short8*)(arow + c8 * 8);
        unsigned int rb = (unsigned)(4095 - c8 * 8);
        #pragma unroll
        for (int jj = 0; jj < 8; ++jj) {
            unsigned int b = (unsigned short)x8[jj];
            unsigned int sr = (unsigned)((int)(b << 16) >> 31);    // 0 or all-ones
            unsigned int mono = b ^ ((sr >> 17) | 0x8000u);        // order-preserving
            unsigned int keyv = (mono << 16) | (rb - jj);
            if (keyv > v[7]) {
                unsigned int x = keyv;
                #pragma unroll
                for (int s = 0; s < 8; ++s) {
                    unsigned int hi = v[s] > x ? v[s] : x;
                    unsigned int lo = v[s] > x ? x : v[s];
                    v[s] = hi; x = lo;
                }
            }
        }
    }

    // ---- extract global top-16 via wave-max pops ----
    unsigned int sk[KC];
    #pragma unroll
    for (int k = 0; k < KC; ++k) {
        unsigned int bv = v[0];
        #pragma unroll
        for (int d = 1; d < 64; d <<= 1) {
            unsigned int ov = (unsigned)__shfl_xor((int)bv, d);
            bv = bv > ov ? bv : ov;
        }
        sk[k] = bv;
        bool won = (v[0] == bv);
        #pragma unroll
        for (int s = 0; s < 7; ++s) v[s] = won ? v[s + 1] : v[s];
        v[7] = won ? 0u : v[7];
    }

    int civ[KC];
    #pragma unroll
    for (int s = 0; s < KC; ++s) civ[s] = 4095 - (int)(sk[s] & 0xFFFFu);

    // ---- refine: candidate c = lane&15, slice g = lane>>4, fp64 dot ----
    int c = lane & 15, g = lane >> 4;
    int cidx = civ[0];
    #pragma unroll
    for (int s = 1; s < KC; ++s) cidx = (c == s) ? civ[s] : cidx;
    const float* qrow = qf + row * Dd;
    const float* krow = key + (long long)cidx * Dd;
    double dacc = 0.0;
    #pragma unroll
    for (int i = 0; i < 16; ++i) {
        float4 qv = *(const float4*)(qrow + g * 64 + i * 4);
        float4 kv = *(const float4*)(krow + g * 64 + i * 4);
        dacc = fma((double)qv.x, (double)kv.x, dacc);
        dacc = fma((double)qv.y, (double)kv.y, dacc);
        dacc = fma((double)qv.z, (double)kv.z, dacc);
        dacc = fma((double)qv.w, (double)kv.w, dacc);
    }
    dacc += __shfl_xor(dacc, 16);
    dacc += __shfl_xor(dacc, 32);
    float rvf = (float)dacc;

    float cv[KC];
    #pragma unroll
    for (int s = 0; s < KC; ++s) cv[s] = __shfl(rvf, s);

    // ---- all-pairs rank on (refined value desc, idx asc); selected = rank<8 ----
    unsigned int m32[KC];
    #pragma unroll
    for (int s = 0; s < KC; ++s) {
        unsigned int fb = __float_as_uint(cv[s]);
        m32[s] = fb ^ ((unsigned)((int)fb >> 31) | 0x80000000u);
    }
    bool sel[KC];
    #pragma unroll
    for (int s = 0; s < KC; ++s) {
        int r = 0;
        #pragma unroll
        for (int t = 0; t < KC; ++t) {
            if (t != s) {
                bool gt = (m32[t] > m32[s]) || (m32[t] == m32[s] && civ[t] < civ[s]);
                r += gt ? 1 : 0;
            }
        }
        sel[s] = (r < KSEL);
    }

    // ---- softmax over selected ----
    float mx = cv[0];
    #pragma unroll
    for (int s = 1; s < KC; ++s) mx = fmaxf(mx, cv[s]);
    float p[KC]; float z = 0.f;
    #pragma unroll
    for (int s = 0; s < KC; ++s) { p[s] = sel[s] ? expf(cv[s] - mx) : 0.f; z += p[s]; }
    float inv = 1.f / z;
    #pragma unroll
    for (int s = 0; s < KC; ++s) p[s] *= inv;

    // ---- mem_retrieved (reads mem rows; overwrites q row after full read) ----
    {
        float4 a = make_float4(0.f, 0.f, 0.f, 0.f);
        #pragma unroll
        for (int s = 0; s < KC; ++s) {
            if (sel[s]) {
                const float4 mv = *(const float4*)(mem + (long long)civ[s] * Dd + lane * 4);
                a.x = fmaf(p[s], mv.x, a.x); a.y = fmaf(p[s], mv.y, a.y);
                a.z = fmaf(p[s], mv.z, a.z); a.w = fmaf(p[s], mv.w, a.w);
            }
        }
        *(float4*)(memr + row * Dd + lane * 4) = a;
    }

    if (lane < Ee) {
        float s8 = 0.f;
        #pragma unroll
        for (int s = 0; s < KC; ++s)
            if (sel[s]) s8 = fmaf(p[s], mlab[(long long)civ[s] * Ee + lane], s8);
        gate[row * Ee + lane] = s8;
        labr[row * Ee + lane] = s8;
    }

    // ---- att_w row: NT zero-fill, barrier (drains stores), sparse insert ----
    float* awrow = attw + row * Mm;
    {
        f32x4 zz = (f32x4){0.f, 0.f, 0.f, 0.f};
        #pragma unroll
        for (int t = 0; t < 16; ++t)
            __builtin_nontemporal_store(zz, (f32x4*)(awrow + (t * 64 + lane) * 4));
    }
    __syncthreads();   // s_waitcnt vmcnt(0) + barrier: zero-stores ordered before inserts
    if (lane < KC) {
        float myp = p[0]; int myi = civ[0];
        #pragma unroll
        for (int s = 1; s < KC; ++s) {
            myp = (lane == s) ? p[s] : myp;
            myi = (lane == s) ? civ[s] : myi;
        }
        awrow[myi] = myp;   // unselected lanes write 0.0 at their own idx (true value is 0.0)
    }
}

extern "C" void kernel_launch(void* const* d_in, const int* in_sizes, int n_in,
                              void* d_out, int out_size, void* d_ws, size_t ws_size,
                              hipStream_t stream) {
    const float* prop = (const float*)d_in[0];
    const float* W    = (const float*)d_in[2];
    const float* bias = (const float*)d_in[3];
    const float* key  = (const float*)d_in[4];
    const float* mem  = (const float*)d_in[5];
    const float* wg   = (const float*)d_in[6];

    float* out  = (float*)d_out;
    float* gate = out + O_GATE;
    float* memr = out + O_MEMR;
    float* labr = out + O_LABR;
    float* mlab = out + O_MLAB;
    float* attw = out + O_ATTW;

    char* ws = (char*)d_ws;
    float*          WT   = (float*)(ws + WS_WT);
    unsigned short* kh   = (unsigned short*)(ws + WS_KH);
    unsigned short* attH = (unsigned short*)(ws + WS_ATTH);
    unsigned short* qh   = (unsigned short*)(ws + WS_QH);
    float*          qf   = memr;   // fp32 q in memr output region (dead before overwrite)

    k_transpose<<<256, 256, 0, stream>>>(W, WT);
    k_q<<<ROWS / 16, 256, 0, stream>>>(prop, WT, bias, qf, qh);
    k_key16<<<(Mm * Dd) / 256, 256, 0, stream>>>(key, kh);
    k_mlabel<<<Mm / 256, 256, 0, stream>>>(mem, wg, mlab);
    k_att<<<4096, 256, 0, stream>>>(qh, kh, attH);
    k_final2<<<ROWS / 4, 256, 0, stream>>>(attH, qf, key, mem, mlab, gate, memr, labr, attw);
}